// Round 2
// baseline (47.504 us; speedup 1.0000x reference)
//
#include <hip/hip_runtime.h>

// LengthRegulator: out[b,t,:] = x[b, searchsorted(cumsum(dur[b]), t, 'right'), :]
// for t < len[b] = min(sum(dur[b]), max_len), else 0. Second output: len[b].
//
// Fully fused: each block recomputes the (tiny) cumsum for its example in LDS.
// Memory-bound: ~201 MB streaming stores + ~50 MB gathered reads.
// R1: 42.2 us (5.97 TB/s effective). R2 change: nontemporal stores for the
// output stream (never re-read; keep L2 for the 3.5x-reused x rows) + unroll.

#define TPB   512   // threads per block (8 waves)
#define TROWS 128   // output frames per block
#define SMAX  512   // max phonemes supported by the in-LDS scan

typedef float f32x4 __attribute__((ext_vector_type(4)));

template <int CD4>
__global__ __launch_bounds__(TPB)
void lr_kernel(const float* __restrict__ xf, const int* __restrict__ dur,
               float* __restrict__ out, int B, int S, int T, int rtD4) {
    const int D4 = CD4 ? CD4 : rtD4;   // float4s per row (D/4); 96 in the bench

    __shared__ int csum[SMAX];
    __shared__ int idxs[TROWS];

    const int b     = blockIdx.x;
    const int chunk = blockIdx.y;
    const int tid   = threadIdx.x;

    // ---- load + clamp durations, inclusive scan over SMAX entries ----
    int dv = 0;
    if (tid < S) {
        dv = dur[(size_t)b * S + tid];
        dv = dv < 0 ? 0 : (dv > 300 ? 300 : dv);   // torch clamp(0, 300)
    }
    csum[tid] = dv;
    __syncthreads();
#pragma unroll
    for (int off = 1; off < SMAX; off <<= 1) {
        int v   = csum[tid];
        int add = (tid >= off) ? csum[tid - off] : 0;
        __syncthreads();
        csum[tid] = v + add;
        __syncthreads();
    }
    const int total = csum[SMAX - 1];
    const int len   = total < T ? total : T;       // min(total, max_len); T == max_len

    // ---- binary search (searchsorted side='right') for this block's frames ----
    const int t0 = chunk * TROWS;
    if (tid < TROWS) {
        const int t = t0 + tid;
        int lo = 0, hi = S;
        while (lo < hi) {
            int mid = (lo + hi) >> 1;
            if (csum[mid] <= t) lo = mid + 1; else hi = mid;
        }
        idxs[tid] = lo < S ? lo : S - 1;           // clip(idx, 0, S-1)
    }
    __syncthreads();

    // ---- streamed gather: TROWS rows x D4 float4, coalesced both sides ----
    const f32x4* xb = (const f32x4*)xf + (size_t)b * S * D4;
    f32x4*       ob = (f32x4*)out + ((size_t)b * T + t0) * D4;
    const int nelem = TROWS * D4;
#pragma unroll 4
    for (int e = tid; e < nelem; e += TPB) {
        const int r = e / D4;          // compile-time D4 -> magic-mul
        const int c = e - r * D4;
        const int t = t0 + r;
        f32x4 v = {0.f, 0.f, 0.f, 0.f};
        if (t < len) v = xb[(size_t)idxs[r] * D4 + c];
        if (t < T)   __builtin_nontemporal_store(v, &ob[e]);
    }

    // ---- second output: lengths[b] as float32 value ----
    if (chunk == 0 && tid == 0) {
        out[(size_t)B * T * (size_t)(D4 * 4) + b] = (float)len;
    }
}

extern "C" void kernel_launch(void* const* d_in, const int* in_sizes, int n_in,
                              void* d_out, int out_size, void* d_ws, size_t ws_size,
                              hipStream_t stream) {
    const float* x   = (const float*)d_in[0];
    const int*   dur = (const int*)d_in[1];
    float*       out = (float*)d_out;

    // Derive shapes: in_sizes[0] = B*S*D, in_sizes[1] = B*S,
    // out_size = B*(T*D + 1). Unique under S <= SMAX.
    const long long n_x = in_sizes[0], n_dur = in_sizes[1];
    const int D = (int)(n_x / n_dur);
    long long B = 0, S = 0, T = 0;
    for (long long b = 1; b <= n_dur; ++b) {
        if (n_dur % b) continue;
        const long long s = n_dur / b;
        if (s > SMAX) continue;
        const long long rem = (long long)out_size - b;
        if (rem <= 0) break;
        if (rem % ((long long)D * b)) continue;
        B = b; S = s; T = rem / ((long long)D * b);
        break;
    }
    if (!B) { B = 64; S = 512; T = 2048; }   // bench shapes fallback

    const int D4 = D / 4;
    dim3 grid((unsigned)B, (unsigned)((T + TROWS - 1) / TROWS));
    if (D % 4 == 0 && D4 == 96) {
        lr_kernel<96><<<grid, TPB, 0, stream>>>(x, dur, out,
                                                (int)B, (int)S, (int)T, D4);
    } else if (D % 4 == 0) {
        lr_kernel<0><<<grid, TPB, 0, stream>>>(x, dur, out,
                                               (int)B, (int)S, (int)T, D4);
    }
}

// Round 3
// 41.159 us; speedup vs baseline: 1.1542x; 1.1542x over previous
//
#include <hip/hip_runtime.h>

// LengthRegulator: out[b,t,:] = x[b, searchsorted(cumsum(dur[b]), t, 'right'), :]
// for t < len[b] = min(sum(dur[b]), max_len), else 0. Second output: len[b].
//
// Memory-bound: ~201 MB streaming stores + ~50 MB gathered reads.
// R1: 42.2 us (plain stores, 18-barrier scan, TROWS=128).
// R2: 47.5 us — nontemporal stores REGRESSED (-12%); reverted.
// R3: shuffle-based scan (3 barriers instead of 18) + TROWS=256 (half the
//     prologues chip-wide). Streaming loop identical to R1.

#define TPB   512   // threads per block (8 waves)
#define TROWS 256   // output frames per block
#define SMAX  512   // max phonemes supported by the in-LDS scan

typedef float f32x4 __attribute__((ext_vector_type(4)));

template <int CD4>
__global__ __launch_bounds__(TPB)
void lr_kernel(const float* __restrict__ xf, const int* __restrict__ dur,
               float* __restrict__ out, int B, int S, int T, int rtD4) {
    const int D4 = CD4 ? CD4 : rtD4;   // float4s per row (D/4); 96 in the bench

    __shared__ int csum[SMAX];
    __shared__ int wsum[8];
    __shared__ int idxs[TROWS];

    const int b     = blockIdx.x;
    const int chunk = blockIdx.y;
    const int tid   = threadIdx.x;
    const int lane  = tid & 63;
    const int wave  = tid >> 6;

    // ---- load + clamp durations; wave-shuffle inclusive scan (3 barriers) ----
    int dv = 0;
    if (tid < S) {
        dv = dur[(size_t)b * S + tid];
        dv = dv < 0 ? 0 : (dv > 300 ? 300 : dv);   // torch clamp(0, 300)
    }
    int v = dv;
#pragma unroll
    for (int off = 1; off < 64; off <<= 1) {
        int n = __shfl_up(v, off, 64);
        if (lane >= off) v += n;
    }
    if (lane == 63) wsum[wave] = v;
    __syncthreads();
    if (wave == 0 && lane < 8) {
        int w = wsum[lane];
#pragma unroll
        for (int off = 1; off < 8; off <<= 1) {
            int n = __shfl_up(w, off, 64);
            if (lane >= off) w += n;
        }
        wsum[lane] = w;
    }
    __syncthreads();
    if (wave > 0) v += wsum[wave - 1];
    csum[tid] = v;
    __syncthreads();

    const int total = csum[SMAX - 1];
    const int len   = total < T ? total : T;       // min(total, max_len); T == max_len

    // ---- binary search (searchsorted side='right') for this block's frames ----
    const int t0 = chunk * TROWS;
    if (tid < TROWS) {
        const int t = t0 + tid;
        int lo = 0, hi = S;
        while (lo < hi) {
            int mid = (lo + hi) >> 1;
            if (csum[mid] <= t) lo = mid + 1; else hi = mid;
        }
        idxs[tid] = lo < S ? lo : S - 1;           // clip(idx, 0, S-1)
    }
    __syncthreads();

    // ---- streamed gather: TROWS rows x D4 float4, coalesced both sides ----
    const f32x4* xb = (const f32x4*)xf + (size_t)b * S * D4;
    f32x4*       ob = (f32x4*)out + ((size_t)b * T + t0) * D4;
    const int nelem = TROWS * D4;
#pragma unroll 4
    for (int e = tid; e < nelem; e += TPB) {
        const int r = e / D4;          // compile-time D4 -> magic-mul
        const int c = e - r * D4;
        const int t = t0 + r;
        f32x4 w = {0.f, 0.f, 0.f, 0.f};
        if (t < len) w = xb[(size_t)idxs[r] * D4 + c];
        if (t < T)   ob[e] = w;
    }

    // ---- second output: lengths[b] as float32 value ----
    if (chunk == 0 && tid == 0) {
        out[(size_t)B * T * (size_t)(D4 * 4) + b] = (float)len;
    }
}

extern "C" void kernel_launch(void* const* d_in, const int* in_sizes, int n_in,
                              void* d_out, int out_size, void* d_ws, size_t ws_size,
                              hipStream_t stream) {
    const float* x   = (const float*)d_in[0];
    const int*   dur = (const int*)d_in[1];
    float*       out = (float*)d_out;

    // Derive shapes: in_sizes[0] = B*S*D, in_sizes[1] = B*S,
    // out_size = B*(T*D + 1). Unique under S <= SMAX.
    const long long n_x = in_sizes[0], n_dur = in_sizes[1];
    const int D = (int)(n_x / n_dur);
    long long B = 0, S = 0, T = 0;
    for (long long b = 1; b <= n_dur; ++b) {
        if (n_dur % b) continue;
        const long long s = n_dur / b;
        if (s > SMAX) continue;
        const long long rem = (long long)out_size - b;
        if (rem <= 0) break;
        if (rem % ((long long)D * b)) continue;
        B = b; S = s; T = rem / ((long long)D * b);
        break;
    }
    if (!B) { B = 64; S = 512; T = 2048; }   // bench shapes fallback

    const int D4 = D / 4;
    dim3 grid((unsigned)B, (unsigned)((T + TROWS - 1) / TROWS));
    if (D % 4 == 0 && D4 == 96) {
        lr_kernel<96><<<grid, TPB, 0, stream>>>(x, dur, out,
                                                (int)B, (int)S, (int)T, D4);
    } else if (D % 4 == 0) {
        lr_kernel<0><<<grid, TPB, 0, stream>>>(x, dur, out,
                                               (int)B, (int)S, (int)T, D4);
    }
}